// Round 5
// baseline (561.304 us; speedup 1.0000x reference)
//
#include <hip/hip_runtime.h>
#include <hip/hip_bf16.h>

typedef short short8 __attribute__((ext_vector_type(8)));
typedef float f32x4 __attribute__((ext_vector_type(4)));
typedef unsigned int uint4v __attribute__((ext_vector_type(4)));

#define NEDGE 800000
#define NNODE 100000
#define HD    128
#define TM    64          // edges per block
#define LDA3  520         // Abuf row stride ush: [geo 0,256) [desc 256,512) [pad 8]
                          // 1040 B/row: 16B-aligned rows, 260 dw = 4 mod 32 (balanced b128)
#define LDF   144         // fused bf16 row stride (288 B, 16B-aligned, 8 mod 32 dw)
#define LDH1  80
#define LDH2  48
// sub-buffer bases (ush offsets inside Abuf; geo+desc both dead when these go live)
#define OFF_FUSED 0
#define OFF_H1    9216     // 64*144
#define OFF_H2    14336    // + 64*80
#define OFF_OSTG  17408    // + 64*48  (byte 34816, 16B-aligned; f32 64x26 = 3328 ush)

// workspace layout (ushort elems)
#define WOFF_NFB   142336
#define WOFF_DESCB (142336 + 12800000)
#define WS_NEED    ((size_t)(142336 + 2 * 12800000) * 2)

__device__ __forceinline__ unsigned short f2bf(float f) {
    unsigned int u = __float_as_uint(f);
    unsigned int r = u + 0x7fffu + ((u >> 16) & 1u);   // RNE
    return (unsigned short)(r >> 16);
}
__device__ __forceinline__ float bf2f(unsigned short u) {
    union { unsigned int i; float f; } v; v.i = ((unsigned int)u) << 16; return v.f;
}
// packed fp32x2 -> bf16x2 (v_cvt_pk_bf16_f32 on gfx950)
__device__ __forceinline__ unsigned int pk_bf16(float a, float b) {
    __hip_bfloat162 h = __float22bfloat162_rn(make_float2(a, b));
    union { __hip_bfloat162 h2; unsigned int u; } c; c.h2 = h; return c.u;
}

// Blocks [0,556): pack all 7 fp32 weights [K][N] into bf16 per-lane MFMA B-fragment order.
// Blocks [556,25556): convert nf/desc fp32 tables -> bf16 tables (fully coalesced).
__global__ void pack_convert(const float* __restrict__ We, const float* __restrict__ Wq,
                             const float* __restrict__ Wk, const float* __restrict__ Wv,
                             const float* __restrict__ Wc1, const float* __restrict__ Wc2,
                             const float* __restrict__ Wc3,
                             const float* __restrict__ nf, const float* __restrict__ desc,
                             unsigned short* __restrict__ ws) {
    int b = blockIdx.x;
    if (b >= 556) {
        int cb = b - 556;
        const float* src; unsigned short* dst;
        if (cb < 12500) { src = nf;   dst = ws + WOFF_NFB; }
        else            { src = desc; dst = ws + WOFF_DESCB; cb -= 12500; }
        long i = ((long)cb * 256 + threadIdx.x) * 4;
        f32x4 v = *(const f32x4*)(src + i);
        uint2 o;
        o.x = pk_bf16(v[0], v[1]);
        o.y = pk_bf16(v[2], v[3]);
        *(uint2*)(dst + i) = o;
        return;
    }
    const float* src; unsigned short* dst; int KT, NT, ncols;
    if (b < 512) {
        int sel = b >> 7;
        src = sel == 0 ? We : sel == 1 ? Wq : sel == 2 ? Wk : Wv;
        dst = ws + sel * 32768;
        KT = 8; NT = 8; ncols = 128; b &= 127;
    } else if (b < 544) { src = Wc1; dst = ws + 131072; KT = 4; NT = 4; ncols = 64; b -= 512; }
    else if (b < 552)   { src = Wc2; dst = ws + 139264; KT = 2; NT = 2; ncols = 32; b -= 544; }
    else                { src = Wc3; dst = ws + 141312; KT = 1; NT = 2; ncols = 26; b -= 552; }
    int idx = b * 256 + threadIdx.x;
    int total = NT * KT * 64 * 8;
    if (idx >= total) return;
    int j = idx & 7;
    int l = (idx >> 3) & 63;
    int rem = idx >> 9;
    int s = rem % KT;
    int t = rem / KT;
    int k = s * 32 + ((l >> 4) << 3) + j;
    int n = t * 16 + (l & 15);
    dst[idx] = (n < ncols) ? f2bf(src[k * ncols + n]) : (unsigned short)0;
}

template<bool TAB>
__global__ __launch_bounds__(256, 2)
void fused_relcls(const float* __restrict__ nf,
                  const float* __restrict__ desc,
                  const int* __restrict__ sub, const int* __restrict__ obj,
                  const unsigned short* __restrict__ nfb, const unsigned short* __restrict__ descb,
                  const unsigned short* __restrict__ wef, const unsigned short* __restrict__ wqf,
                  const unsigned short* __restrict__ wkf, const unsigned short* __restrict__ wvf,
                  const unsigned short* __restrict__ wc1f, const unsigned short* __restrict__ wc2f,
                  const unsigned short* __restrict__ wc3f,
                  const float* __restrict__ be, const float* __restrict__ bq,
                  const float* __restrict__ bk, const float* __restrict__ bv,
                  const float* __restrict__ bc1, const float* __restrict__ bc2,
                  const float* __restrict__ bc3,
                  float* __restrict__ out)
{
    // LDS 67584 B -> 2 blocks/CU -> 2 waves/EU -> 256-reg budget (128 arch + 128 acc).
    // Register plan: AGPR accO..accV peak 96/128; VGPR opk16+a16+bw32+addr ~90/128.
    __shared__ __align__(16) unsigned short Abuf[TM * LDA3];  // 66560 B
    __shared__ float ssm[TM * 4];                             // 1024 B

    const int t  = threadIdx.x;
    const int w  = t >> 6;       // wave 0..3 (owns cols [w*32, w*32+32))
    const int l  = t & 63;
    const int cl = l & 15;
    const int cq = l >> 4;
    const long e0 = (long)blockIdx.x * TM;
    const int wu = __builtin_amdgcn_readfirstlane(w);
    const int half = l >> 5;     // lanes 0-31: sub half, 32-63: obj half
    const int ci   = l & 31;

    // ---------------- stage BOTH tables (single latency exposure) ----------------
    if constexpr (TAB) {
        #pragma unroll
        for (int i = 0; i < 16; ++i) {
            int e = wu + 4 * i;
            int idx = half ? obj[e0 + e] : sub[e0 + e];
            uint2 g = *(const uint2*)(nfb + (long)idx * HD + ci * 4);
            uint2 d = *(const uint2*)(descb + (long)idx * HD + ci * 4);
            *(uint2*)&Abuf[e * LDA3 + half * HD + ci * 4] = g;
            *(uint2*)&Abuf[e * LDA3 + 256 + half * HD + ci * 4] = d;
        }
    } else {
        #pragma unroll
        for (int i = 0; i < 16; ++i) {
            int e = wu + 4 * i;
            int idx = half ? obj[e0 + e] : sub[e0 + e];
            f32x4 v = *(const f32x4*)(nf + (long)idx * HD + ci * 4);
            uint2 o; o.x = pk_bf16(v[0], v[1]); o.y = pk_bf16(v[2], v[3]);
            *(uint2*)&Abuf[e * LDA3 + half * HD + ci * 4] = o;
            f32x4 v2 = *(const f32x4*)(desc + (long)idx * HD + ci * 4);
            uint2 o2; o2.x = pk_bf16(v2[0], v2[1]); o2.y = pk_bf16(v2[2], v2[3]);
            *(uint2*)&Abuf[e * LDA3 + 256 + half * HD + ci * 4] = o2;
        }
    }
    __syncthreads();   // B1: tile staged

    f32x4 accQ[4][2], accV[4][2];   // live into fused phase
    unsigned int opk[16];           // origin parked as packed bf16

    // ---------------- merged O+Q: shared geo A-fragments, 16 MFMA per ks ----------------
    {
        f32x4 accO[4][2];
        float bO0 = be[w * 32 + cl], bO1 = be[w * 32 + 16 + cl];
        float bQ0 = bq[w * 32 + cl], bQ1 = bq[w * 32 + 16 + cl];
        #pragma unroll
        for (int m = 0; m < 4; ++m) {
            accO[m][0] = (f32x4){bO0, bO0, bO0, bO0};
            accO[m][1] = (f32x4){bO1, bO1, bO1, bO1};
            accQ[m][0] = (f32x4){bQ0, bQ0, bQ0, bQ0};
            accQ[m][1] = (f32x4){bQ1, bQ1, bQ1, bQ1};
        }
        #pragma unroll
        for (int ks = 0; ks < 8; ++ks) {
            short8 a[4];
            #pragma unroll
            for (int m = 0; m < 4; ++m)
                a[m] = *(const short8*)&Abuf[(m * 16 + cl) * LDA3 + ks * 32 + cq * 8];
            short8 bwe[2], bwq[2];
            #pragma unroll
            for (int tt = 0; tt < 2; ++tt) {
                bwe[tt] = *(const short8*)&wef[(((w * 2 + tt) * 8 + ks) * 64 + l) * 8];
                bwq[tt] = *(const short8*)&wqf[(((w * 2 + tt) * 8 + ks) * 64 + l) * 8];
            }
            #pragma unroll
            for (int m = 0; m < 4; ++m)
                #pragma unroll
                for (int tt = 0; tt < 2; ++tt) {
                    accO[m][tt] = __builtin_amdgcn_mfma_f32_16x16x32_bf16(a[m], bwe[tt], accO[m][tt], 0, 0, 0);
                    accQ[m][tt] = __builtin_amdgcn_mfma_f32_16x16x32_bf16(a[m], bwq[tt], accQ[m][tt], 0, 0, 0);
                }
        }
        #pragma unroll
        for (int m = 0; m < 4; ++m)
            #pragma unroll
            for (int tt = 0; tt < 2; ++tt) {
                opk[m * 4 + tt * 2 + 0] = pk_bf16(accO[m][tt][0], accO[m][tt][1]);
                opk[m * 4 + tt * 2 + 1] = pk_bf16(accO[m][tt][2], accO[m][tt][3]);
            }
    }   // accO dead -> AGPR headroom for K+V

    // ---------------- merged K+V: shared desc A-fragments ----------------
    {
        f32x4 accK[4][2];
        float bK0 = bk[w * 32 + cl], bK1 = bk[w * 32 + 16 + cl];
        float bV0 = bv[w * 32 + cl], bV1 = bv[w * 32 + 16 + cl];
        #pragma unroll
        for (int m = 0; m < 4; ++m) {
            accK[m][0] = (f32x4){bK0, bK0, bK0, bK0};
            accK[m][1] = (f32x4){bK1, bK1, bK1, bK1};
            accV[m][0] = (f32x4){bV0, bV0, bV0, bV0};
            accV[m][1] = (f32x4){bV1, bV1, bV1, bV1};
        }
        #pragma unroll
        for (int ks = 0; ks < 8; ++ks) {
            short8 a[4];
            #pragma unroll
            for (int m = 0; m < 4; ++m)
                a[m] = *(const short8*)&Abuf[(m * 16 + cl) * LDA3 + 256 + ks * 32 + cq * 8];
            short8 bwk[2], bwv[2];
            #pragma unroll
            for (int tt = 0; tt < 2; ++tt) {
                bwk[tt] = *(const short8*)&wkf[(((w * 2 + tt) * 8 + ks) * 64 + l) * 8];
                bwv[tt] = *(const short8*)&wvf[(((w * 2 + tt) * 8 + ks) * 64 + l) * 8];
            }
            #pragma unroll
            for (int m = 0; m < 4; ++m)
                #pragma unroll
                for (int tt = 0; tt < 2; ++tt) {
                    accK[m][tt] = __builtin_amdgcn_mfma_f32_16x16x32_bf16(a[m], bwk[tt], accK[m][tt], 0, 0, 0);
                    accV[m][tt] = __builtin_amdgcn_mfma_f32_16x16x32_bf16(a[m], bwv[tt], accV[m][tt], 0, 0, 0);
                }
        }
        #pragma unroll
        for (int m = 0; m < 4; ++m)
            #pragma unroll
            for (int tt = 0; tt < 2; ++tt)
                accQ[m][tt] *= accK[m][tt];     // S = q .* k (accK dead)
    }

    // ---------------- softmax partials; keep exp(S) in accQ ----------------
    {
        #pragma unroll
        for (int m = 0; m < 4; ++m) {
            float es[4];
            #pragma unroll
            for (int r = 0; r < 4; ++r) {
                float ea = __expf(accQ[m][0][r]);
                float eb = __expf(accQ[m][1][r]);
                accQ[m][0][r] = ea;
                accQ[m][1][r] = eb;
                float s = ea + eb;
                s += __shfl_xor(s, 1);
                s += __shfl_xor(s, 2);
                s += __shfl_xor(s, 4);
                s += __shfl_xor(s, 8);
                es[r] = s;
            }
            if (cl == 0) {
                #pragma unroll
                for (int r = 0; r < 4; ++r)
                    ssm[(m * 16 + cq * 4 + r) * 4 + w] = es[r];
            }
        }
    }
    __syncthreads();   // B2: ssm complete; geo+desc regions dead

    // ---------------- fused = V*alpha + O -> Abuf[OFF_FUSED], stride LDF ----------------
    {
        unsigned short* fusedBuf = Abuf + OFF_FUSED;
        #pragma unroll
        for (int m = 0; m < 4; ++m)
            #pragma unroll
            for (int r = 0; r < 4; ++r) {
                int row = m * 16 + cq * 4 + r;
                f32x4 b = *(const f32x4*)&ssm[row * 4];
                float inv = 1.0f / (b[0] + b[1] + b[2] + b[3]);
                #pragma unroll
                for (int tt = 0; tt < 2; ++tt) {
                    unsigned int word = opk[m * 4 + tt * 2 + (r >> 1)];
                    unsigned short us = (r & 1) ? (unsigned short)(word >> 16) : (unsigned short)(word & 0xffffu);
                    float Oval = bf2f(us);
                    float alpha = accQ[m][tt][r] * inv;
                    float f = accV[m][tt][r] * alpha + Oval;
                    fusedBuf[row * LDF + w * 32 + tt * 16 + cl] = f2bf(f);
                }
            }
    }
    __syncthreads();   // B3: fused staged

    // ---------------- classifier L1: [64,128]@[128,64] + relu -> h1 ----------------
    {
        const unsigned short* fusedBuf = Abuf + OFF_FUSED;
        unsigned short* h1Buf = Abuf + OFF_H1;
        float b1 = bc1[w * 16 + cl];
        f32x4 acc[4];
        #pragma unroll
        for (int m = 0; m < 4; ++m) acc[m] = (f32x4){b1, b1, b1, b1};
        #pragma unroll
        for (int ks = 0; ks < 4; ++ks) {
            short8 a[4];
            #pragma unroll
            for (int m = 0; m < 4; ++m)
                a[m] = *(const short8*)&fusedBuf[(m * 16 + cl) * LDF + ks * 32 + cq * 8];
            short8 bw = *(const short8*)&wc1f[((w * 4 + ks) * 64 + l) * 8];
            #pragma unroll
            for (int m = 0; m < 4; ++m)
                acc[m] = __builtin_amdgcn_mfma_f32_16x16x32_bf16(a[m], bw, acc[m], 0, 0, 0);
        }
        #pragma unroll
        for (int m = 0; m < 4; ++m)
            #pragma unroll
            for (int r = 0; r < 4; ++r)
                h1Buf[(m * 16 + cq * 4 + r) * LDH1 + w * 16 + cl] = f2bf(fmaxf(acc[m][r], 0.f));
    }
    __syncthreads();   // B4

    // ---------------- classifier L2: [64,64]@[64,32] -> h2 ----------------
    {
        const unsigned short* h1Buf = Abuf + OFF_H1;
        unsigned short* h2Buf = Abuf + OFF_H2;
        int tn = w & 1, mh = w >> 1;
        float b2 = bc2[tn * 16 + cl];
        f32x4 acc[2];
        acc[0] = (f32x4){b2, b2, b2, b2};
        acc[1] = (f32x4){b2, b2, b2, b2};
        #pragma unroll
        for (int ks = 0; ks < 2; ++ks) {
            short8 a[2];
            #pragma unroll
            for (int mm = 0; mm < 2; ++mm)
                a[mm] = *(const short8*)&h1Buf[((mh * 2 + mm) * 16 + cl) * LDH1 + ks * 32 + cq * 8];
            short8 bw = *(const short8*)&wc2f[((tn * 2 + ks) * 64 + l) * 8];
            #pragma unroll
            for (int mm = 0; mm < 2; ++mm)
                acc[mm] = __builtin_amdgcn_mfma_f32_16x16x32_bf16(a[mm], bw, acc[mm], 0, 0, 0);
        }
        #pragma unroll
        for (int mm = 0; mm < 2; ++mm)
            #pragma unroll
            for (int r = 0; r < 4; ++r)
                h2Buf[((mh * 2 + mm) * 16 + cq * 4 + r) * LDH2 + tn * 16 + cl] = f2bf(acc[mm][r]);
    }
    __syncthreads();   // B5

    // ---------------- classifier L3: [64,32]@[32,26] -> ostg f32 ----------------
    {
        const unsigned short* h2Buf = Abuf + OFF_H2;
        float* ostg = (float*)(Abuf + OFF_OSTG);
        f32x4 acc[2];
        #pragma unroll
        for (int tt = 0; tt < 2; ++tt) {
            int col = tt * 16 + cl;
            float b3 = (col < 26) ? bc3[col] : 0.f;
            acc[tt] = (f32x4){b3, b3, b3, b3};
        }
        short8 a = *(const short8*)&h2Buf[(w * 16 + cl) * LDH2 + cq * 8];
        #pragma unroll
        for (int tt = 0; tt < 2; ++tt)
            acc[tt] = __builtin_amdgcn_mfma_f32_16x16x32_bf16(a, *(const short8*)&wc3f[(tt * 64 + l) * 8], acc[tt], 0, 0, 0);
        #pragma unroll
        for (int tt = 0; tt < 2; ++tt) {
            int col = tt * 16 + cl;
            if (col < 26) {
                #pragma unroll
                for (int r = 0; r < 4; ++r)
                    ostg[(w * 16 + cq * 4 + r) * 26 + col] = acc[tt][r];
            }
        }
    }
    __syncthreads();   // B6

    // ---------------- coalesced block output: 6656 contiguous bytes ----------------
    {
        const uint4v* src = (const uint4v*)(Abuf + OFF_OSTG);
        uint4v* dst = (uint4v*)(out + e0 * 26);
        #pragma unroll
        for (int k2 = 0; k2 < 2; ++k2) {
            int idx = t + k2 * 256;
            if (idx < 416)
                dst[idx] = src[idx];
        }
    }
}

extern "C" void kernel_launch(void* const* d_in, const int* in_sizes, int n_in,
                              void* d_out, int out_size, void* d_ws, size_t ws_size,
                              hipStream_t stream) {
    const float* nf   = (const float*)d_in[0];
    const float* desc = (const float*)d_in[1];
    const int* sub = (const int*)d_in[2];
    const int* obj = (const int*)d_in[3];
    const float* We  = (const float*)d_in[4];
    const float* be  = (const float*)d_in[5];
    const float* Wq  = (const float*)d_in[6];
    const float* bq  = (const float*)d_in[7];
    const float* Wk  = (const float*)d_in[8];
    const float* bk  = (const float*)d_in[9];
    const float* Wv  = (const float*)d_in[10];
    const float* bv  = (const float*)d_in[11];
    const float* Wc1 = (const float*)d_in[12];
    const float* bc1 = (const float*)d_in[13];
    const float* Wc2 = (const float*)d_in[14];
    const float* bc2 = (const float*)d_in[15];
    const float* Wc3 = (const float*)d_in[16];
    const float* bc3 = (const float*)d_in[17];

    unsigned short* ws = (unsigned short*)d_ws;
    unsigned short* wef  = ws;                 // 8*8*64*8  = 32768 elems
    unsigned short* wqf  = ws + 32768;
    unsigned short* wkf  = ws + 65536;
    unsigned short* wvf  = ws + 98304;
    unsigned short* wc1f = ws + 131072;        // 4*4*64*8 = 8192
    unsigned short* wc2f = ws + 139264;        // 2*2*64*8 = 2048
    unsigned short* wc3f = ws + 141312;        // 1*2*64*8 = 1024
    unsigned short* nfb   = ws + WOFF_NFB;     // 12.8M elems (25.6 MB)
    unsigned short* descb = ws + WOFF_DESCB;   // 12.8M elems (25.6 MB)

    const bool tab = (ws_size >= WS_NEED);
    const int prep_grid = tab ? (556 + 25000) : 556;

    pack_convert<<<prep_grid, 256, 0, stream>>>(We, Wq, Wk, Wv, Wc1, Wc2, Wc3, nf, desc, ws);

    if (tab) {
        fused_relcls<true><<<NEDGE / TM, 256, 0, stream>>>(
            nf, desc, sub, obj, nfb, descb,
            wef, wqf, wkf, wvf, wc1f, wc2f, wc3f,
            be, bq, bk, bv, bc1, bc2, bc3,
            (float*)d_out);
    } else {
        fused_relcls<false><<<NEDGE / TM, 256, 0, stream>>>(
            nf, desc, sub, obj, nfb, descb,
            wef, wqf, wkf, wvf, wc1f, wc2f, wc3f,
            be, bq, bk, bv, bc1, bc2, bc3,
            (float*)d_out);
    }
}

// Round 6
// 552.190 us; speedup vs baseline: 1.0165x; 1.0165x over previous
//
#include <hip/hip_runtime.h>
#include <hip/hip_bf16.h>

typedef short short8 __attribute__((ext_vector_type(8)));
typedef float f32x4 __attribute__((ext_vector_type(4)));
typedef unsigned int uint4v __attribute__((ext_vector_type(4)));

#define NEDGE 800000
#define NNODE 100000
#define HD    128
#define TM    64          // edges per block
// LDS arena (ush offsets inside Abuf[16384], 32768 B total):
//   stage planes: sub rows [0,8192), obj rows [8192,16384), row stride 128 ush (256 B)
//   after B4:     fused [0,8704) stride 136; h1 [8704,13312) stride 72; h2 [13312,15872) stride 40
//   after B7:     ostg f32 [0,3328) ush (6656 B)
#define LDF   136
#define LDH1  72
#define LDH2  40

// workspace layout (ushort elems)
#define WOFF_NFB   142336
#define WOFF_DESCB (142336 + 12800000)
#define WS_NEED    ((size_t)(142336 + 2 * 12800000) * 2)

__device__ __forceinline__ unsigned short f2bf(float f) {
    unsigned int u = __float_as_uint(f);
    unsigned int r = u + 0x7fffu + ((u >> 16) & 1u);   // RNE
    return (unsigned short)(r >> 16);
}
__device__ __forceinline__ float bf2f(unsigned short u) {
    union { unsigned int i; float f; } v; v.i = ((unsigned int)u) << 16; return v.f;
}
// packed fp32x2 -> bf16x2 (v_cvt_pk_bf16_f32 on gfx950)
__device__ __forceinline__ unsigned int pk_bf16(float a, float b) {
    __hip_bfloat162 h = __float22bfloat162_rn(make_float2(a, b));
    union { __hip_bfloat162 h2; unsigned int u; } c; c.h2 = h; return c.u;
}
// async global->LDS, 16 B per lane, dest = uniform base + lane*16 (HW rule, m104)
__device__ __forceinline__ void gload_lds16(const unsigned short* g, unsigned short* lds) {
    __builtin_amdgcn_global_load_lds(
        (const __attribute__((address_space(1))) unsigned int*)g,
        (__attribute__((address_space(3))) unsigned int*)lds, 16, 0, 0);
}

// Blocks [0,556): pack all 7 fp32 weights [K][N] into bf16 per-lane MFMA B-fragment order.
// Blocks [556,25556): convert nf/desc fp32 tables -> bf16 tables (fully coalesced).
__global__ void pack_convert(const float* __restrict__ We, const float* __restrict__ Wq,
                             const float* __restrict__ Wk, const float* __restrict__ Wv,
                             const float* __restrict__ Wc1, const float* __restrict__ Wc2,
                             const float* __restrict__ Wc3,
                             const float* __restrict__ nf, const float* __restrict__ desc,
                             unsigned short* __restrict__ ws) {
    int b = blockIdx.x;
    if (b >= 556) {
        int cb = b - 556;
        const float* src; unsigned short* dst;
        if (cb < 12500) { src = nf;   dst = ws + WOFF_NFB; }
        else            { src = desc; dst = ws + WOFF_DESCB; cb -= 12500; }
        long i = ((long)cb * 256 + threadIdx.x) * 4;
        f32x4 v = *(const f32x4*)(src + i);
        uint2 o;
        o.x = pk_bf16(v[0], v[1]);
        o.y = pk_bf16(v[2], v[3]);
        *(uint2*)(dst + i) = o;
        return;
    }
    const float* src; unsigned short* dst; int KT, NT, ncols;
    if (b < 512) {
        int sel = b >> 7;
        src = sel == 0 ? We : sel == 1 ? Wq : sel == 2 ? Wk : Wv;
        dst = ws + sel * 32768;
        KT = 8; NT = 8; ncols = 128; b &= 127;
    } else if (b < 544) { src = Wc1; dst = ws + 131072; KT = 4; NT = 4; ncols = 64; b -= 512; }
    else if (b < 552)   { src = Wc2; dst = ws + 139264; KT = 2; NT = 2; ncols = 32; b -= 544; }
    else                { src = Wc3; dst = ws + 141312; KT = 1; NT = 2; ncols = 26; b -= 552; }
    int idx = b * 256 + threadIdx.x;
    int total = NT * KT * 64 * 8;
    if (idx >= total) return;
    int j = idx & 7;
    int l = (idx >> 3) & 63;
    int rem = idx >> 9;
    int s = rem % KT;
    int t = rem / KT;
    int k = s * 32 + ((l >> 4) << 3) + j;
    int n = t * 16 + (l & 15);
    dst[idx] = (n < ncols) ? f2bf(src[k * ncols + n]) : (unsigned short)0;
}

template<bool TAB>
__global__ __launch_bounds__(256, 4)
void fused_relcls(const float* __restrict__ nf,
                  const float* __restrict__ desc,
                  const int* __restrict__ sub, const int* __restrict__ obj,
                  const unsigned short* __restrict__ nfb, const unsigned short* __restrict__ descb,
                  const unsigned short* __restrict__ wef, const unsigned short* __restrict__ wqf,
                  const unsigned short* __restrict__ wkf, const unsigned short* __restrict__ wvf,
                  const unsigned short* __restrict__ wc1f, const unsigned short* __restrict__ wc2f,
                  const unsigned short* __restrict__ wc3f,
                  const float* __restrict__ be, const float* __restrict__ bq,
                  const float* __restrict__ bk, const float* __restrict__ bv,
                  const float* __restrict__ bc1, const float* __restrict__ bc2,
                  const float* __restrict__ bc3,
                  float* __restrict__ out)
{
    // 32768 + 1024 = 33792 B LDS -> 4 blocks/CU.
    __shared__ __align__(16) unsigned short Abuf[16384];
    __shared__ float ssm[TM * 4];
    unsigned short* h1Buf = Abuf + 8704;
    unsigned short* h2Buf = Abuf + 13312;

    const int t  = threadIdx.x;
    const int w  = t >> 6;       // wave 0..3 (owns cols [w*32, w*32+32))
    const int l  = t & 63;
    const int cl = l & 15;       // chunk slot / col-in-tile / row-in-tile
    const int cq = l >> 4;       // quad / row-in-group
    const long e0 = (long)blockIdx.x * TM;
    const int wu = __builtin_amdgcn_readfirstlane(w);
    const int rbase = wu * 16;   // wave stages rows [rbase, rbase+16)

    // ---------------- stage geo planes (async direct-to-LDS, swizzled source) ----------------
    // LDS slot (row r, chunk cl) holds global 16B chunk (cl ^ (r&15)) of that row.
    if constexpr (TAB) {
        int si4[4], oi4[4], cg4[4];
        #pragma unroll
        for (int g = 0; g < 4; ++g) {
            int r = rbase + g * 4 + cq;
            si4[g] = sub[e0 + r];
            oi4[g] = obj[e0 + r];
            cg4[g] = (cl ^ (r & 15)) << 3;   // ush offset of fetched chunk
        }
        #pragma unroll
        for (int g = 0; g < 4; ++g) {
            gload_lds16(nfb + (long)si4[g] * HD + cg4[g], &Abuf[(rbase + g * 4) * 128]);
            gload_lds16(nfb + (long)oi4[g] * HD + cg4[g], &Abuf[8192 + (rbase + g * 4) * 128]);
        }
    } else {
        #pragma unroll
        for (int g = 0; g < 4; ++g) {
            int r = rbase + g * 4 + cq;
            int si = sub[e0 + r], oi = obj[e0 + r];
            int cgf = (cl ^ (r & 15)) << 3;  // float index of fetched chunk
            f32x4 v0 = *(const f32x4*)(nf + (long)si * HD + cgf);
            f32x4 v1 = *(const f32x4*)(nf + (long)si * HD + cgf + 4);
            uint4v o;
            o.x = pk_bf16(v0[0], v0[1]); o.y = pk_bf16(v0[2], v0[3]);
            o.z = pk_bf16(v1[0], v1[1]); o.w = pk_bf16(v1[2], v1[3]);
            *(uint4v*)&Abuf[r * 128 + cl * 8] = o;
            f32x4 u0 = *(const f32x4*)(nf + (long)oi * HD + cgf);
            f32x4 u1 = *(const f32x4*)(nf + (long)oi * HD + cgf + 4);
            uint4v o2;
            o2.x = pk_bf16(u0[0], u0[1]); o2.y = pk_bf16(u0[2], u0[3]);
            o2.z = pk_bf16(u1[0], u1[1]); o2.w = pk_bf16(u1[2], u1[3]);
            *(uint4v*)&Abuf[8192 + r * 128 + cl * 8] = o2;
        }
    }
    __syncthreads();   // B1 (vmcnt(0) drains the staging loads)

    f32x4 acc0[4][2], acc1[4][2];   // two live accumulator matrices (64 AGPR)
    unsigned int opk[16];           // origin parked as packed bf16

    // ---------------- O-phase: origin = geo@We + be -> pack to opk ----------------
    {
        float b0 = be[w * 32 + cl], b1 = be[w * 32 + 16 + cl];
        #pragma unroll
        for (int m = 0; m < 4; ++m) {
            acc0[m][0] = (f32x4){b0, b0, b0, b0};
            acc0[m][1] = (f32x4){b1, b1, b1, b1};
        }
        #pragma unroll
        for (int ks = 0; ks < 8; ++ks) {
            const unsigned short* pl = Abuf + ((ks < 4) ? 0 : 8192);
            const int ch = ((((ks & 3) << 2) | cq) ^ cl) << 3;
            short8 a[4];
            #pragma unroll
            for (int m = 0; m < 4; ++m)
                a[m] = *(const short8*)&pl[(m * 16 + cl) * 128 + ch];
            short8 bw[2];
            #pragma unroll
            for (int tt = 0; tt < 2; ++tt)
                bw[tt] = *(const short8*)&wef[(((w * 2 + tt) * 8 + ks) * 64 + l) * 8];
            #pragma unroll
            for (int m = 0; m < 4; ++m)
                #pragma unroll
                for (int tt = 0; tt < 2; ++tt)
                    acc0[m][tt] = __builtin_amdgcn_mfma_f32_16x16x32_bf16(a[m], bw[tt], acc0[m][tt], 0, 0, 0);
        }
        #pragma unroll
        for (int m = 0; m < 4; ++m)
            #pragma unroll
            for (int tt = 0; tt < 2; ++tt) {
                opk[m * 4 + tt * 2 + 0] = pk_bf16(acc0[m][tt][0], acc0[m][tt][1]);
                opk[m * 4 + tt * 2 + 1] = pk_bf16(acc0[m][tt][2], acc0[m][tt][3]);
            }
    }

    // ---------------- Q-phase: query = geo@Wq + bq (reuses acc0) ----------------
    {
        float b0 = bq[w * 32 + cl], b1 = bq[w * 32 + 16 + cl];
        #pragma unroll
        for (int m = 0; m < 4; ++m) {
            acc0[m][0] = (f32x4){b0, b0, b0, b0};
            acc0[m][1] = (f32x4){b1, b1, b1, b1};
        }
        #pragma unroll
        for (int ks = 0; ks < 8; ++ks) {
            const unsigned short* pl = Abuf + ((ks < 4) ? 0 : 8192);
            const int ch = ((((ks & 3) << 2) | cq) ^ cl) << 3;
            short8 a[4];
            #pragma unroll
            for (int m = 0; m < 4; ++m)
                a[m] = *(const short8*)&pl[(m * 16 + cl) * 128 + ch];
            short8 bw[2];
            #pragma unroll
            for (int tt = 0; tt < 2; ++tt)
                bw[tt] = *(const short8*)&wqf[(((w * 2 + tt) * 8 + ks) * 64 + l) * 8];
            #pragma unroll
            for (int m = 0; m < 4; ++m)
                #pragma unroll
                for (int tt = 0; tt < 2; ++tt)
                    acc0[m][tt] = __builtin_amdgcn_mfma_f32_16x16x32_bf16(a[m], bw[tt], acc0[m][tt], 0, 0, 0);
        }
    }
    __syncthreads();   // B2: all geo reads done

    // ---------------- stage desc planes (same swizzled scheme) ----------------
    if constexpr (TAB) {
        int si4[4], oi4[4], cg4[4];
        #pragma unroll
        for (int g = 0; g < 4; ++g) {
            int r = rbase + g * 4 + cq;
            si4[g] = sub[e0 + r];
            oi4[g] = obj[e0 + r];
            cg4[g] = (cl ^ (r & 15)) << 3;
        }
        #pragma unroll
        for (int g = 0; g < 4; ++g) {
            gload_lds16(descb + (long)si4[g] * HD + cg4[g], &Abuf[(rbase + g * 4) * 128]);
            gload_lds16(descb + (long)oi4[g] * HD + cg4[g], &Abuf[8192 + (rbase + g * 4) * 128]);
        }
    } else {
        #pragma unroll
        for (int g = 0; g < 4; ++g) {
            int r = rbase + g * 4 + cq;
            int si = sub[e0 + r], oi = obj[e0 + r];
            int cgf = (cl ^ (r & 15)) << 3;
            f32x4 v0 = *(const f32x4*)(desc + (long)si * HD + cgf);
            f32x4 v1 = *(const f32x4*)(desc + (long)si * HD + cgf + 4);
            uint4v o;
            o.x = pk_bf16(v0[0], v0[1]); o.y = pk_bf16(v0[2], v0[3]);
            o.z = pk_bf16(v1[0], v1[1]); o.w = pk_bf16(v1[2], v1[3]);
            *(uint4v*)&Abuf[r * 128 + cl * 8] = o;
            f32x4 u0 = *(const f32x4*)(desc + (long)oi * HD + cgf);
            f32x4 u1 = *(const f32x4*)(desc + (long)oi * HD + cgf + 4);
            uint4v o2;
            o2.x = pk_bf16(u0[0], u0[1]); o2.y = pk_bf16(u0[2], u0[3]);
            o2.z = pk_bf16(u1[0], u1[1]); o2.w = pk_bf16(u1[2], u1[3]);
            *(uint4v*)&Abuf[8192 + r * 128 + cl * 8] = o2;
        }
    }
    __syncthreads();   // B3

    // ---------------- K-phase: key = desc@Wk + bk -> acc1; S = Q.*K in acc0 ----------------
    {
        float b0 = bk[w * 32 + cl], b1 = bk[w * 32 + 16 + cl];
        #pragma unroll
        for (int m = 0; m < 4; ++m) {
            acc1[m][0] = (f32x4){b0, b0, b0, b0};
            acc1[m][1] = (f32x4){b1, b1, b1, b1};
        }
        #pragma unroll
        for (int ks = 0; ks < 8; ++ks) {
            const unsigned short* pl = Abuf + ((ks < 4) ? 0 : 8192);
            const int ch = ((((ks & 3) << 2) | cq) ^ cl) << 3;
            short8 a[4];
            #pragma unroll
            for (int m = 0; m < 4; ++m)
                a[m] = *(const short8*)&pl[(m * 16 + cl) * 128 + ch];
            short8 bw[2];
            #pragma unroll
            for (int tt = 0; tt < 2; ++tt)
                bw[tt] = *(const short8*)&wkf[(((w * 2 + tt) * 8 + ks) * 64 + l) * 8];
            #pragma unroll
            for (int m = 0; m < 4; ++m)
                #pragma unroll
                for (int tt = 0; tt < 2; ++tt)
                    acc1[m][tt] = __builtin_amdgcn_mfma_f32_16x16x32_bf16(a[m], bw[tt], acc1[m][tt], 0, 0, 0);
        }
        #pragma unroll
        for (int m = 0; m < 4; ++m)
            #pragma unroll
            for (int tt = 0; tt < 2; ++tt)
                acc0[m][tt] *= acc1[m][tt];     // S = q .* k (acc1 now free)
    }

    // ---------------- softmax partials; store exp(S) back into acc0 ----------------
    {
        #pragma unroll
        for (int m = 0; m < 4; ++m) {
            float es[4];
            #pragma unroll
            for (int r = 0; r < 4; ++r) {
                float ea = __expf(acc0[m][0][r]);
                float eb = __expf(acc0[m][1][r]);
                acc0[m][0][r] = ea;
                acc0[m][1][r] = eb;
                float s = ea + eb;
                s += __shfl_xor(s, 1);
                s += __shfl_xor(s, 2);
                s += __shfl_xor(s, 4);
                s += __shfl_xor(s, 8);
                es[r] = s;
            }
            if (cl == 0) {
                #pragma unroll
                for (int r = 0; r < 4; ++r)
                    ssm[(m * 16 + cq * 4 + r) * 4 + w] = es[r];
            }
        }
    }

    // ---------------- V-phase: value = desc@Wv + bv -> acc1 ----------------
    {
        float b0 = bv[w * 32 + cl], b1 = bv[w * 32 + 16 + cl];
        #pragma unroll
        for (int m = 0; m < 4; ++m) {
            acc1[m][0] = (f32x4){b0, b0, b0, b0};
            acc1[m][1] = (f32x4){b1, b1, b1, b1};
        }
        #pragma unroll
        for (int ks = 0; ks < 8; ++ks) {
            const unsigned short* pl = Abuf + ((ks < 4) ? 0 : 8192);
            const int ch = ((((ks & 3) << 2) | cq) ^ cl) << 3;
            short8 a[4];
            #pragma unroll
            for (int m = 0; m < 4; ++m)
                a[m] = *(const short8*)&pl[(m * 16 + cl) * 128 + ch];
            short8 bw[2];
            #pragma unroll
            for (int tt = 0; tt < 2; ++tt)
                bw[tt] = *(const short8*)&wvf[(((w * 2 + tt) * 8 + ks) * 64 + l) * 8];
            #pragma unroll
            for (int m = 0; m < 4; ++m)
                #pragma unroll
                for (int tt = 0; tt < 2; ++tt)
                    acc1[m][tt] = __builtin_amdgcn_mfma_f32_16x16x32_bf16(a[m], bw[tt], acc1[m][tt], 0, 0, 0);
        }
    }
    __syncthreads();   // B4: desc reads done, softmax partials visible

    // ---------------- fused = V*alpha + O -> LDS bf16 (A-layout, stride LDF) ----------------
    {
        unsigned short* fusedBuf = Abuf;
        #pragma unroll
        for (int m = 0; m < 4; ++m)
            #pragma unroll
            for (int r = 0; r < 4; ++r) {
                int row = m * 16 + cq * 4 + r;
                f32x4 b = *(const f32x4*)&ssm[row * 4];
                float inv = 1.0f / (b[0] + b[1] + b[2] + b[3]);
                #pragma unroll
                for (int tt = 0; tt < 2; ++tt) {
                    unsigned int word = opk[m * 4 + tt * 2 + (r >> 1)];
                    unsigned short us = (r & 1) ? (unsigned short)(word >> 16) : (unsigned short)(word & 0xffffu);
                    float Oval = bf2f(us);
                    float alpha = acc0[m][tt][r] * inv;
                    float f = acc1[m][tt][r] * alpha + Oval;
                    fusedBuf[row * LDF + w * 32 + tt * 16 + cl] = f2bf(f);
                }
            }
    }
    __syncthreads();   // B5

    // ---------------- classifier L1: [64,128]@[128,64] + relu ----------------
    {
        const unsigned short* fusedBuf = Abuf;
        float b1 = bc1[w * 16 + cl];
        f32x4 acc[4];
        #pragma unroll
        for (int m = 0; m < 4; ++m) acc[m] = (f32x4){b1, b1, b1, b1};
        #pragma unroll
        for (int ks = 0; ks < 4; ++ks) {
            short8 a[4];
            #pragma unroll
            for (int m = 0; m < 4; ++m)
                a[m] = *(const short8*)&fusedBuf[(m * 16 + cl) * LDF + ks * 32 + cq * 8];
            short8 bw = *(const short8*)&wc1f[((w * 4 + ks) * 64 + l) * 8];
            #pragma unroll
            for (int m = 0; m < 4; ++m)
                acc[m] = __builtin_amdgcn_mfma_f32_16x16x32_bf16(a[m], bw, acc[m], 0, 0, 0);
        }
        #pragma unroll
        for (int m = 0; m < 4; ++m)
            #pragma unroll
            for (int r = 0; r < 4; ++r)
                h1Buf[(m * 16 + cq * 4 + r) * LDH1 + w * 16 + cl] = f2bf(fmaxf(acc[m][r], 0.f));
    }
    __syncthreads();   // B6

    // ---------------- classifier L2: [64,64]@[64,32] (no relu) ----------------
    {
        int tn = w & 1, mh = w >> 1;
        float b2 = bc2[tn * 16 + cl];
        f32x4 acc[2];
        acc[0] = (f32x4){b2, b2, b2, b2};
        acc[1] = (f32x4){b2, b2, b2, b2};
        #pragma unroll
        for (int ks = 0; ks < 2; ++ks) {
            short8 a[2];
            #pragma unroll
            for (int mm = 0; mm < 2; ++mm)
                a[mm] = *(const short8*)&h1Buf[((mh * 2 + mm) * 16 + cl) * LDH1 + ks * 32 + cq * 8];
            short8 bw = *(const short8*)&wc2f[((tn * 2 + ks) * 64 + l) * 8];
            #pragma unroll
            for (int mm = 0; mm < 2; ++mm)
                acc[mm] = __builtin_amdgcn_mfma_f32_16x16x32_bf16(a[mm], bw, acc[mm], 0, 0, 0);
        }
        #pragma unroll
        for (int mm = 0; mm < 2; ++mm)
            #pragma unroll
            for (int r = 0; r < 4; ++r)
                h2Buf[((mh * 2 + mm) * 16 + cq * 4 + r) * LDH2 + tn * 16 + cl] = f2bf(acc[mm][r]);
    }
    __syncthreads();   // B7

    // ---------------- classifier L3: [64,32]@[32,26] -> stage f32 in LDS ----------------
    {
        f32x4 acc[2];
        #pragma unroll
        for (int tt = 0; tt < 2; ++tt) {
            int col = tt * 16 + cl;
            float b3 = (col < 26) ? bc3[col] : 0.f;
            acc[tt] = (f32x4){b3, b3, b3, b3};
        }
        short8 a = *(const short8*)&h2Buf[(w * 16 + cl) * LDH2 + cq * 8];
        #pragma unroll
        for (int tt = 0; tt < 2; ++tt)
            acc[tt] = __builtin_amdgcn_mfma_f32_16x16x32_bf16(a, *(const short8*)&wc3f[(tt * 64 + l) * 8], acc[tt], 0, 0, 0);
        float* ostg = (float*)Abuf;
        #pragma unroll
        for (int tt = 0; tt < 2; ++tt) {
            int col = tt * 16 + cl;
            if (col < 26) {
                #pragma unroll
                for (int r = 0; r < 4; ++r)
                    ostg[(w * 16 + cq * 4 + r) * 26 + col] = acc[tt][r];
            }
        }
    }
    __syncthreads();   // B8

    // ---------------- coalesced block output: 6656 contiguous bytes as 416 x 16B ----------------
    {
        const uint4v* src = (const uint4v*)Abuf;
        uint4v* dst = (uint4v*)(out + e0 * 26);
        #pragma unroll
        for (int k2 = 0; k2 < 2; ++k2) {
            int idx = t + k2 * 256;
            if (idx < 416)
                dst[idx] = src[idx];
        }
    }
}

extern "C" void kernel_launch(void* const* d_in, const int* in_sizes, int n_in,
                              void* d_out, int out_size, void* d_ws, size_t ws_size,
                              hipStream_t stream) {
    const float* nf   = (const float*)d_in[0];
    const float* desc = (const float*)d_in[1];
    const int* sub = (const int*)d_in[2];
    const int* obj = (const int*)d_in[3];
    const float* We  = (const float*)d_in[4];
    const float* be  = (const float*)d_in[5];
    const float* Wq  = (const float*)d_in[6];
    const float* bq  = (const float*)d_in[7];
    const float* Wk  = (const float*)d_in[8];
    const float* bk  = (const float*)d_in[9];
    const float* Wv  = (const float*)d_in[10];
    const float* bv  = (const float*)d_in[11];
    const float* Wc1 = (const float*)d_in[12];
    const float* bc1 = (const float*)d_in[13];
    const float* Wc2 = (const float*)d_in[14];
    const float* bc2 = (const float*)d_in[15];
    const float* Wc3 = (const float*)d_in[16];
    const float* bc3 = (const float*)d_in[17];

    unsigned short* ws = (unsigned short*)d_ws;
    unsigned short* wef  = ws;                 // 8*8*64*8  = 32768 elems
    unsigned short* wqf  = ws + 32768;
    unsigned short* wkf  = ws + 65536;
    unsigned short* wvf  = ws + 98304;
    unsigned short* wc1f = ws + 131072;        // 4*4*64*8 = 8192
    unsigned short* wc2f = ws + 139264;        // 2*2*64*8 = 2048
    unsigned short* wc3f = ws + 141312;        // 1*2*64*8 = 1024
    unsigned short* nfb   = ws + WOFF_NFB;     // 12.8M elems (25.6 MB)
    unsigned short* descb = ws + WOFF_DESCB;   // 12.8M elems (25.6 MB)

    const bool tab = (ws_size >= WS_NEED);
    const int prep_grid = tab ? (556 + 25000) : 556;

    pack_convert<<<prep_grid, 256, 0, stream>>>(We, Wq, Wk, Wv, Wc1, Wc2, Wc3, nf, desc, ws);

    if (tab) {
        fused_relcls<true><<<NEDGE / TM, 256, 0, stream>>>(
            nf, desc, sub, obj, nfb, descb,
            wef, wqf, wkf, wvf, wc1f, wc2f, wc3f,
            be, bq, bk, bv, bc1, bc2, bc3,
            (float*)d_out);
    } else {
        fused_relcls<false><<<NEDGE / TM, 256, 0, stream>>>(
            nf, desc, sub, obj, nfb, descb,
            wef, wqf, wkf, wvf, wc1f, wc2f, wc3f,
            be, bq, bk, bv, bc1, bc2, bc3,
            (float*)d_out);
    }
}

// Round 7
// 509.341 us; speedup vs baseline: 1.1020x; 1.0841x over previous
//
#include <hip/hip_runtime.h>
#include <hip/hip_bf16.h>

typedef short short8 __attribute__((ext_vector_type(8)));
typedef float f32x4 __attribute__((ext_vector_type(4)));
typedef unsigned int uint4v __attribute__((ext_vector_type(4)));

#define NEDGE 800000
#define NNODE 100000
#define HD    128
#define TM    64          // edges per block
// LDS arena: two staging planes, each 16 groups (4 rows x 256 B) at stride 1056 B.
//   plane0 (sub rows): ush [0, 8448)     plane1 (obj rows): ush [8448, 16896)
//   group stride 528 ush (264 dw == 8 mod 32 -> conflict-free a-reads, linear addressing)
//   after B4 overlays (planes dead): fused [0,8704) stride 136; h1 [8704,13312) stride 72;
//                                    h2 [13312,15872) stride 40; ostg f32 [0,3328) ush
#define GRP   528         // ush per 4-row group (1056 B)
#define PL1   8448        // ush offset of plane 1
#define LDF   136
#define LDH1  72
#define LDH2  40

// workspace layout (ushort elems)
#define WOFF_NFB   142336
#define WOFF_DESCB (142336 + 12800000)
#define WS_NEED    ((size_t)(142336 + 2 * 12800000) * 2)

__device__ __forceinline__ unsigned short f2bf(float f) {
    unsigned int u = __float_as_uint(f);
    unsigned int r = u + 0x7fffu + ((u >> 16) & 1u);   // RNE
    return (unsigned short)(r >> 16);
}
__device__ __forceinline__ float bf2f(unsigned short u) {
    union { unsigned int i; float f; } v; v.i = ((unsigned int)u) << 16; return v.f;
}
// packed fp32x2 -> bf16x2 (v_cvt_pk_bf16_f32 on gfx950)
__device__ __forceinline__ unsigned int pk_bf16(float a, float b) {
    __hip_bfloat162 h = __float22bfloat162_rn(make_float2(a, b));
    union { __hip_bfloat162 h2; unsigned int u; } c; c.h2 = h; return c.u;
}
// async global->LDS, 16 B per lane, dest = uniform base + lane*16 (HW rule, m104)
__device__ __forceinline__ void gload_lds16(const unsigned short* g, unsigned short* lds) {
    __builtin_amdgcn_global_load_lds(
        (const __attribute__((address_space(1))) unsigned int*)g,
        (__attribute__((address_space(3))) unsigned int*)lds, 16, 0, 0);
}

// Blocks [0,556): pack all 7 fp32 weights [K][N] into bf16 per-lane MFMA B-fragment order.
// Blocks [556,25556): convert nf/desc fp32 tables -> bf16 tables (fully coalesced).
__global__ void pack_convert(const float* __restrict__ We, const float* __restrict__ Wq,
                             const float* __restrict__ Wk, const float* __restrict__ Wv,
                             const float* __restrict__ Wc1, const float* __restrict__ Wc2,
                             const float* __restrict__ Wc3,
                             const float* __restrict__ nf, const float* __restrict__ desc,
                             unsigned short* __restrict__ ws) {
    int b = blockIdx.x;
    if (b >= 556) {
        int cb = b - 556;
        const float* src; unsigned short* dst;
        if (cb < 12500) { src = nf;   dst = ws + WOFF_NFB; }
        else            { src = desc; dst = ws + WOFF_DESCB; cb -= 12500; }
        long i = ((long)cb * 256 + threadIdx.x) * 4;
        f32x4 v = *(const f32x4*)(src + i);
        uint2 o;
        o.x = pk_bf16(v[0], v[1]);
        o.y = pk_bf16(v[2], v[3]);
        *(uint2*)(dst + i) = o;
        return;
    }
    const float* src; unsigned short* dst; int KT, NT, ncols;
    if (b < 512) {
        int sel = b >> 7;
        src = sel == 0 ? We : sel == 1 ? Wq : sel == 2 ? Wk : Wv;
        dst = ws + sel * 32768;
        KT = 8; NT = 8; ncols = 128; b &= 127;
    } else if (b < 544) { src = Wc1; dst = ws + 131072; KT = 4; NT = 4; ncols = 64; b -= 512; }
    else if (b < 552)   { src = Wc2; dst = ws + 139264; KT = 2; NT = 2; ncols = 32; b -= 544; }
    else                { src = Wc3; dst = ws + 141312; KT = 1; NT = 2; ncols = 26; b -= 552; }
    int idx = b * 256 + threadIdx.x;
    int total = NT * KT * 64 * 8;
    if (idx >= total) return;
    int j = idx & 7;
    int l = (idx >> 3) & 63;
    int rem = idx >> 9;
    int s = rem % KT;
    int t = rem / KT;
    int k = s * 32 + ((l >> 4) << 3) + j;
    int n = t * 16 + (l & 15);
    dst[idx] = (n < ncols) ? f2bf(src[k * ncols + n]) : (unsigned short)0;
}

template<bool TAB>
__global__ __launch_bounds__(256, 4)
void fused_relcls(const float* __restrict__ nf,
                  const float* __restrict__ desc,
                  const int* __restrict__ sub, const int* __restrict__ obj,
                  const unsigned short* __restrict__ nfb, const unsigned short* __restrict__ descb,
                  const unsigned short* __restrict__ wef, const unsigned short* __restrict__ wqf,
                  const unsigned short* __restrict__ wkf, const unsigned short* __restrict__ wvf,
                  const unsigned short* __restrict__ wc1f, const unsigned short* __restrict__ wc2f,
                  const unsigned short* __restrict__ wc3f,
                  const float* __restrict__ be, const float* __restrict__ bq,
                  const float* __restrict__ bk, const float* __restrict__ bv,
                  const float* __restrict__ bc1, const float* __restrict__ bc2,
                  const float* __restrict__ bc3,
                  float* __restrict__ out)
{
    // 33792 + 1024 = 34816 B LDS -> 4 blocks/CU.
    __shared__ __align__(16) unsigned short Abuf[16896];
    __shared__ float ssm[TM * 4];
    unsigned short* h1Buf = Abuf + 8704;
    unsigned short* h2Buf = Abuf + 13312;

    const int t  = threadIdx.x;
    const int w  = t >> 6;       // wave 0..3 (owns cols [w*32, w*32+32))
    const int l  = t & 63;
    const int cl = l & 15;       // chunk slot / col-in-tile / row-in-tile
    const int cq = l >> 4;       // quad / row-in-group
    const long e0 = (long)blockIdx.x * TM;
    const int wu = __builtin_amdgcn_readfirstlane(w);
    const int rbase = wu * 16;   // wave stages rows [rbase, rbase+16)
    const int g0 = wu * 4;       // wave's first group index

    // per-lane base into a plane for a-fragment reads (linear in m, ks afterwards):
    //   addr(r = m*16+cl, chunk = (ks&3)*4+cq) = m*2112 + (cl>>2)*528 + (cl&3)*128 + (ks&3)*32 + cq*8
    const int abase = (cl >> 2) * GRP + (cl & 3) * 128 + cq * 8;

    // ---------------- stage geo planes (async direct-to-LDS, linear source) ----------------
    if constexpr (TAB) {
        int si4[4], oi4[4];
        #pragma unroll
        for (int g = 0; g < 4; ++g) {
            int r = rbase + g * 4 + cq;
            si4[g] = sub[e0 + r];
            oi4[g] = obj[e0 + r];
        }
        #pragma unroll
        for (int g = 0; g < 4; ++g) {
            gload_lds16(nfb + (long)si4[g] * HD + (cl << 3), &Abuf[(g0 + g) * GRP]);
            gload_lds16(nfb + (long)oi4[g] * HD + (cl << 3), &Abuf[PL1 + (g0 + g) * GRP]);
        }
    } else {
        #pragma unroll
        for (int g = 0; g < 4; ++g) {
            int r = rbase + g * 4 + cq;
            int si = sub[e0 + r], oi = obj[e0 + r];
            int dst = (g0 + g) * GRP + cq * 128 + cl * 8;
            f32x4 v0 = *(const f32x4*)(nf + (long)si * HD + cl * 8);
            f32x4 v1 = *(const f32x4*)(nf + (long)si * HD + cl * 8 + 4);
            uint4v o;
            o.x = pk_bf16(v0[0], v0[1]); o.y = pk_bf16(v0[2], v0[3]);
            o.z = pk_bf16(v1[0], v1[1]); o.w = pk_bf16(v1[2], v1[3]);
            *(uint4v*)&Abuf[dst] = o;
            f32x4 u0 = *(const f32x4*)(nf + (long)oi * HD + cl * 8);
            f32x4 u1 = *(const f32x4*)(nf + (long)oi * HD + cl * 8 + 4);
            uint4v o2;
            o2.x = pk_bf16(u0[0], u0[1]); o2.y = pk_bf16(u0[2], u0[3]);
            o2.z = pk_bf16(u1[0], u1[1]); o2.w = pk_bf16(u1[2], u1[3]);
            *(uint4v*)&Abuf[PL1 + dst] = o2;
        }
    }
    __syncthreads();   // B1 (vmcnt(0) drains the staging loads)

    f32x4 acc0[4][2], acc1[4][2];   // two live accumulator matrices (64 AGPR peak)
    unsigned int opk[16];           // origin parked as packed bf16

    // ---------------- O-phase: origin = geo@We + be -> pack to opk ----------------
    {
        float b0 = be[w * 32 + cl], b1 = be[w * 32 + 16 + cl];
        #pragma unroll
        for (int m = 0; m < 4; ++m) {
            acc0[m][0] = (f32x4){b0, b0, b0, b0};
            acc0[m][1] = (f32x4){b1, b1, b1, b1};
        }
        #pragma unroll
        for (int ks = 0; ks < 8; ++ks) {
            const unsigned short* pl = Abuf + ((ks < 4) ? 0 : PL1);
            short8 a[4];
            #pragma unroll
            for (int m = 0; m < 4; ++m)
                a[m] = *(const short8*)&pl[m * 2112 + abase + (ks & 3) * 32];
            short8 bw[2];
            #pragma unroll
            for (int tt = 0; tt < 2; ++tt)
                bw[tt] = *(const short8*)&wef[(((w * 2 + tt) * 8 + ks) * 64 + l) * 8];
            #pragma unroll
            for (int m = 0; m < 4; ++m)
                #pragma unroll
                for (int tt = 0; tt < 2; ++tt)
                    acc0[m][tt] = __builtin_amdgcn_mfma_f32_16x16x32_bf16(a[m], bw[tt], acc0[m][tt], 0, 0, 0);
        }
        #pragma unroll
        for (int m = 0; m < 4; ++m)
            #pragma unroll
            for (int tt = 0; tt < 2; ++tt) {
                opk[m * 4 + tt * 2 + 0] = pk_bf16(acc0[m][tt][0], acc0[m][tt][1]);
                opk[m * 4 + tt * 2 + 1] = pk_bf16(acc0[m][tt][2], acc0[m][tt][3]);
            }
    }

    // ---------------- Q-phase: query = geo@Wq + bq (reuses acc0) ----------------
    {
        float b0 = bq[w * 32 + cl], b1 = bq[w * 32 + 16 + cl];
        #pragma unroll
        for (int m = 0; m < 4; ++m) {
            acc0[m][0] = (f32x4){b0, b0, b0, b0};
            acc0[m][1] = (f32x4){b1, b1, b1, b1};
        }
        #pragma unroll
        for (int ks = 0; ks < 8; ++ks) {
            const unsigned short* pl = Abuf + ((ks < 4) ? 0 : PL1);
            short8 a[4];
            #pragma unroll
            for (int m = 0; m < 4; ++m)
                a[m] = *(const short8*)&pl[m * 2112 + abase + (ks & 3) * 32];
            short8 bw[2];
            #pragma unroll
            for (int tt = 0; tt < 2; ++tt)
                bw[tt] = *(const short8*)&wqf[(((w * 2 + tt) * 8 + ks) * 64 + l) * 8];
            #pragma unroll
            for (int m = 0; m < 4; ++m)
                #pragma unroll
                for (int tt = 0; tt < 2; ++tt)
                    acc0[m][tt] = __builtin_amdgcn_mfma_f32_16x16x32_bf16(a[m], bw[tt], acc0[m][tt], 0, 0, 0);
        }
    }
    __syncthreads();   // B2: all geo reads done

    // ---------------- stage desc planes (same scheme) ----------------
    if constexpr (TAB) {
        int si4[4], oi4[4];
        #pragma unroll
        for (int g = 0; g < 4; ++g) {
            int r = rbase + g * 4 + cq;
            si4[g] = sub[e0 + r];
            oi4[g] = obj[e0 + r];
        }
        #pragma unroll
        for (int g = 0; g < 4; ++g) {
            gload_lds16(descb + (long)si4[g] * HD + (cl << 3), &Abuf[(g0 + g) * GRP]);
            gload_lds16(descb + (long)oi4[g] * HD + (cl << 3), &Abuf[PL1 + (g0 + g) * GRP]);
        }
    } else {
        #pragma unroll
        for (int g = 0; g < 4; ++g) {
            int r = rbase + g * 4 + cq;
            int si = sub[e0 + r], oi = obj[e0 + r];
            int dst = (g0 + g) * GRP + cq * 128 + cl * 8;
            f32x4 v0 = *(const f32x4*)(desc + (long)si * HD + cl * 8);
            f32x4 v1 = *(const f32x4*)(desc + (long)si * HD + cl * 8 + 4);
            uint4v o;
            o.x = pk_bf16(v0[0], v0[1]); o.y = pk_bf16(v0[2], v0[3]);
            o.z = pk_bf16(v1[0], v1[1]); o.w = pk_bf16(v1[2], v1[3]);
            *(uint4v*)&Abuf[dst] = o;
            f32x4 u0 = *(const f32x4*)(desc + (long)oi * HD + cl * 8);
            f32x4 u1 = *(const f32x4*)(desc + (long)oi * HD + cl * 8 + 4);
            uint4v o2;
            o2.x = pk_bf16(u0[0], u0[1]); o2.y = pk_bf16(u0[2], u0[3]);
            o2.z = pk_bf16(u1[0], u1[1]); o2.w = pk_bf16(u1[2], u1[3]);
            *(uint4v*)&Abuf[PL1 + dst] = o2;
        }
    }
    __syncthreads();   // B3

    // ---------------- K-phase: key = desc@Wk + bk -> acc1; S = Q.*K in acc0 ----------------
    {
        float b0 = bk[w * 32 + cl], b1 = bk[w * 32 + 16 + cl];
        #pragma unroll
        for (int m = 0; m < 4; ++m) {
            acc1[m][0] = (f32x4){b0, b0, b0, b0};
            acc1[m][1] = (f32x4){b1, b1, b1, b1};
        }
        #pragma unroll
        for (int ks = 0; ks < 8; ++ks) {
            const unsigned short* pl = Abuf + ((ks < 4) ? 0 : PL1);
            short8 a[4];
            #pragma unroll
            for (int m = 0; m < 4; ++m)
                a[m] = *(const short8*)&pl[m * 2112 + abase + (ks & 3) * 32];
            short8 bw[2];
            #pragma unroll
            for (int tt = 0; tt < 2; ++tt)
                bw[tt] = *(const short8*)&wkf[(((w * 2 + tt) * 8 + ks) * 64 + l) * 8];
            #pragma unroll
            for (int m = 0; m < 4; ++m)
                #pragma unroll
                for (int tt = 0; tt < 2; ++tt)
                    acc1[m][tt] = __builtin_amdgcn_mfma_f32_16x16x32_bf16(a[m], bw[tt], acc1[m][tt], 0, 0, 0);
        }
        #pragma unroll
        for (int m = 0; m < 4; ++m)
            #pragma unroll
            for (int tt = 0; tt < 2; ++tt)
                acc0[m][tt] *= acc1[m][tt];     // S = q .* k (acc1 now free)
    }

    // ---------------- softmax partials; store exp(S) back into acc0 ----------------
    {
        #pragma unroll
        for (int m = 0; m < 4; ++m) {
            float es[4];
            #pragma unroll
            for (int r = 0; r < 4; ++r) {
                float ea = __expf(acc0[m][0][r]);
                float eb = __expf(acc0[m][1][r]);
                acc0[m][0][r] = ea;
                acc0[m][1][r] = eb;
                float s = ea + eb;
                s += __shfl_xor(s, 1);
                s += __shfl_xor(s, 2);
                s += __shfl_xor(s, 4);
                s += __shfl_xor(s, 8);
                es[r] = s;
            }
            if (cl == 0) {
                #pragma unroll
                for (int r = 0; r < 4; ++r)
                    ssm[(m * 16 + cq * 4 + r) * 4 + w] = es[r];
            }
        }
    }

    // ---------------- V-phase: value = desc@Wv + bv -> acc1 ----------------
    {
        float b0 = bv[w * 32 + cl], b1 = bv[w * 32 + 16 + cl];
        #pragma unroll
        for (int m = 0; m < 4; ++m) {
            acc1[m][0] = (f32x4){b0, b0, b0, b0};
            acc1[m][1] = (f32x4){b1, b1, b1, b1};
        }
        #pragma unroll
        for (int ks = 0; ks < 8; ++ks) {
            const unsigned short* pl = Abuf + ((ks < 4) ? 0 : PL1);
            short8 a[4];
            #pragma unroll
            for (int m = 0; m < 4; ++m)
                a[m] = *(const short8*)&pl[m * 2112 + abase + (ks & 3) * 32];
            short8 bw[2];
            #pragma unroll
            for (int tt = 0; tt < 2; ++tt)
                bw[tt] = *(const short8*)&wvf[(((w * 2 + tt) * 8 + ks) * 64 + l) * 8];
            #pragma unroll
            for (int m = 0; m < 4; ++m)
                #pragma unroll
                for (int tt = 0; tt < 2; ++tt)
                    acc1[m][tt] = __builtin_amdgcn_mfma_f32_16x16x32_bf16(a[m], bw[tt], acc1[m][tt], 0, 0, 0);
        }
    }
    __syncthreads();   // B4: desc reads done, softmax partials visible

    // ---------------- fused = V*alpha + O -> LDS bf16 (A-layout, stride LDF) ----------------
    {
        unsigned short* fusedBuf = Abuf;
        #pragma unroll
        for (int m = 0; m < 4; ++m)
            #pragma unroll
            for (int r = 0; r < 4; ++r) {
                int row = m * 16 + cq * 4 + r;
                f32x4 b = *(const f32x4*)&ssm[row * 4];
                float inv = 1.0f / (b[0] + b[1] + b[2] + b[3]);
                #pragma unroll
                for (int tt = 0; tt < 2; ++tt) {
                    unsigned int word = opk[m * 4 + tt * 2 + (r >> 1)];
                    unsigned short us = (r & 1) ? (unsigned short)(word >> 16) : (unsigned short)(word & 0xffffu);
                    float Oval = bf2f(us);
                    float alpha = acc0[m][tt][r] * inv;
                    float f = acc1[m][tt][r] * alpha + Oval;
                    fusedBuf[row * LDF + w * 32 + tt * 16 + cl] = f2bf(f);
                }
            }
    }
    __syncthreads();   // B5

    // ---------------- classifier L1: [64,128]@[128,64] + relu ----------------
    {
        const unsigned short* fusedBuf = Abuf;
        float b1 = bc1[w * 16 + cl];
        f32x4 acc[4];
        #pragma unroll
        for (int m = 0; m < 4; ++m) acc[m] = (f32x4){b1, b1, b1, b1};
        #pragma unroll
        for (int ks = 0; ks < 4; ++ks) {
            short8 a[4];
            #pragma unroll
            for (int m = 0; m < 4; ++m)
                a[m] = *(const short8*)&fusedBuf[(m * 16 + cl) * LDF + ks * 32 + cq * 8];
            short8 bw = *(const short8*)&wc1f[((w * 4 + ks) * 64 + l) * 8];
            #pragma unroll
            for (int m = 0; m < 4; ++m)
                acc[m] = __builtin_amdgcn_mfma_f32_16x16x32_bf16(a[m], bw, acc[m], 0, 0, 0);
        }
        #pragma unroll
        for (int m = 0; m < 4; ++m)
            #pragma unroll
            for (int r = 0; r < 4; ++r)
                h1Buf[(m * 16 + cq * 4 + r) * LDH1 + w * 16 + cl] = f2bf(fmaxf(acc[m][r], 0.f));
    }
    __syncthreads();   // B6

    // ---------------- classifier L2: [64,64]@[64,32] (no relu) ----------------
    {
        int tn = w & 1, mh = w >> 1;
        float b2 = bc2[tn * 16 + cl];
        f32x4 acc[2];
        acc[0] = (f32x4){b2, b2, b2, b2};
        acc[1] = (f32x4){b2, b2, b2, b2};
        #pragma unroll
        for (int ks = 0; ks < 2; ++ks) {
            short8 a[2];
            #pragma unroll
            for (int mm = 0; mm < 2; ++mm)
                a[mm] = *(const short8*)&h1Buf[((mh * 2 + mm) * 16 + cl) * LDH1 + ks * 32 + cq * 8];
            short8 bw = *(const short8*)&wc2f[((tn * 2 + ks) * 64 + l) * 8];
            #pragma unroll
            for (int mm = 0; mm < 2; ++mm)
                acc[mm] = __builtin_amdgcn_mfma_f32_16x16x32_bf16(a[mm], bw, acc[mm], 0, 0, 0);
        }
        #pragma unroll
        for (int mm = 0; mm < 2; ++mm)
            #pragma unroll
            for (int r = 0; r < 4; ++r)
                h2Buf[((mh * 2 + mm) * 16 + cq * 4 + r) * LDH2 + tn * 16 + cl] = f2bf(acc[mm][r]);
    }
    __syncthreads();   // B7

    // ---------------- classifier L3: [64,32]@[32,26] -> stage f32 in LDS ----------------
    {
        f32x4 acc[2];
        #pragma unroll
        for (int tt = 0; tt < 2; ++tt) {
            int col = tt * 16 + cl;
            float b3 = (col < 26) ? bc3[col] : 0.f;
            acc[tt] = (f32x4){b3, b3, b3, b3};
        }
        short8 a = *(const short8*)&h2Buf[(w * 16 + cl) * LDH2 + cq * 8];
        #pragma unroll
        for (int tt = 0; tt < 2; ++tt)
            acc[tt] = __builtin_amdgcn_mfma_f32_16x16x32_bf16(a, *(const short8*)&wc3f[(tt * 64 + l) * 8], acc[tt], 0, 0, 0);
        float* ostg = (float*)Abuf;
        #pragma unroll
        for (int tt = 0; tt < 2; ++tt) {
            int col = tt * 16 + cl;
            if (col < 26) {
                #pragma unroll
                for (int r = 0; r < 4; ++r)
                    ostg[(w * 16 + cq * 4 + r) * 26 + col] = acc[tt][r];
            }
        }
    }
    __syncthreads();   // B8

    // ---------------- coalesced block output: 6656 contiguous bytes as 416 x 16B ----------------
    {
        const uint4v* src = (const uint4v*)Abuf;
        uint4v* dst = (uint4v*)(out + e0 * 26);
        #pragma unroll
        for (int k2 = 0; k2 < 2; ++k2) {
            int idx = t + k2 * 256;
            if (idx < 416)
                dst[idx] = src[idx];
        }
    }
}

extern "C" void kernel_launch(void* const* d_in, const int* in_sizes, int n_in,
                              void* d_out, int out_size, void* d_ws, size_t ws_size,
                              hipStream_t stream) {
    const float* nf   = (const float*)d_in[0];
    const float* desc = (const float*)d_in[1];
    const int* sub = (const int*)d_in[2];
    const int* obj = (const int*)d_in[3];
    const float* We  = (const float*)d_in[4];
    const float* be  = (const float*)d_in[5];
    const float* Wq  = (const float*)d_in[6];
    const float* bq  = (const float*)d_in[7];
    const float* Wk  = (const float*)d_in[8];
    const float* bk  = (const float*)d_in[9];
    const float* Wv  = (const float*)d_in[10];
    const float* bv  = (const float*)d_in[11];
    const float* Wc1 = (const float*)d_in[12];
    const float* bc1 = (const float*)d_in[13];
    const float* Wc2 = (const float*)d_in[14];
    const float* bc2 = (const float*)d_in[15];
    const float* Wc3 = (const float*)d_in[16];
    const float* bc3 = (const float*)d_in[17];

    unsigned short* ws = (unsigned short*)d_ws;
    unsigned short* wef  = ws;                 // 8*8*64*8  = 32768 elems
    unsigned short* wqf  = ws + 32768;
    unsigned short* wkf  = ws + 65536;
    unsigned short* wvf  = ws + 98304;
    unsigned short* wc1f = ws + 131072;        // 4*4*64*8 = 8192
    unsigned short* wc2f = ws + 139264;        // 2*2*64*8 = 2048
    unsigned short* wc3f = ws + 141312;        // 1*2*64*8 = 1024
    unsigned short* nfb   = ws + WOFF_NFB;     // 12.8M elems (25.6 MB)
    unsigned short* descb = ws + WOFF_DESCB;   // 12.8M elems (25.6 MB)

    const bool tab = (ws_size >= WS_NEED);
    const int prep_grid = tab ? (556 + 25000) : 556;

    pack_convert<<<prep_grid, 256, 0, stream>>>(We, Wq, Wk, Wv, Wc1, Wc2, Wc3, nf, desc, ws);

    if (tab) {
        fused_relcls<true><<<NEDGE / TM, 256, 0, stream>>>(
            nf, desc, sub, obj, nfb, descb,
            wef, wqf, wkf, wvf, wc1f, wc2f, wc3f,
            be, bq, bk, bv, bc1, bc2, bc3,
            (float*)d_out);
    } else {
        fused_relcls<false><<<NEDGE / TM, 256, 0, stream>>>(
            nf, desc, sub, obj, nfb, descb,
            wef, wqf, wkf, wvf, wc1f, wc2f, wc3f,
            be, bq, bk, bv, bc1, bc2, bc3,
            (float*)d_out);
    }
}

// Round 8
// 498.379 us; speedup vs baseline: 1.1263x; 1.0220x over previous
//
#include <hip/hip_runtime.h>
#include <hip/hip_bf16.h>

typedef short short8 __attribute__((ext_vector_type(8)));
typedef float f32x4 __attribute__((ext_vector_type(4)));
typedef unsigned int uint4v __attribute__((ext_vector_type(4)));

#define NEDGE 800000
#define NNODE 100000
#define HD    128
#define TM    64          // edges per block
// LDS arena: two staging planes, each 16 groups (4 rows x 256 B) at stride 1056 B.
//   plane0 (sub rows): ush [0, 8448)     plane1 (obj rows): ush [8448, 16896)
//   XOR chunk swizzle: slot s of in-group row rq holds global 16B chunk (s ^ rq)
//   (staged by fetching chunk cl^cq per lane; LDS dest stays linear for global_load_lds).
//   Read base for chunk c=(ks&3)*4+cq at row rq=cl&3: slot = (ks&3)*4 + (cq^rq) ->
//   per-lane constant + compile-time ks/m offsets; 2-way max bank aliasing per 16-lane phase.
//   after B4 overlays (planes dead): fused [0,8704) stride 136; h1 [8704,13312) stride 72;
//                                    h2 [13312,15872) stride 40; ostg f32 [0,3328) ush
#define GRP   528         // ush per 4-row group (1056 B)
#define PL1   8448        // ush offset of plane 1
#define LDF   136
#define LDH1  72
#define LDH2  40

// workspace layout (ushort elems)
#define WOFF_NFB   142336
#define WOFF_DESCB (142336 + 12800000)
#define WS_NEED    ((size_t)(142336 + 2 * 12800000) * 2)

__device__ __forceinline__ unsigned short f2bf(float f) {
    unsigned int u = __float_as_uint(f);
    unsigned int r = u + 0x7fffu + ((u >> 16) & 1u);   // RNE
    return (unsigned short)(r >> 16);
}
__device__ __forceinline__ float bf2f(unsigned short u) {
    union { unsigned int i; float f; } v; v.i = ((unsigned int)u) << 16; return v.f;
}
// packed fp32x2 -> bf16x2 (v_cvt_pk_bf16_f32 on gfx950)
__device__ __forceinline__ unsigned int pk_bf16(float a, float b) {
    __hip_bfloat162 h = __float22bfloat162_rn(make_float2(a, b));
    union { __hip_bfloat162 h2; unsigned int u; } c; c.h2 = h; return c.u;
}
// async global->LDS, 16 B per lane, dest = uniform base + lane*16 (HW rule, m104)
__device__ __forceinline__ void gload_lds16(const unsigned short* g, unsigned short* lds) {
    __builtin_amdgcn_global_load_lds(
        (const __attribute__((address_space(1))) unsigned int*)g,
        (__attribute__((address_space(3))) unsigned int*)lds, 16, 0, 0);
}

// Blocks [0,556): pack all 7 fp32 weights [K][N] into bf16 per-lane MFMA B-fragment order.
// Blocks [556,25556): convert nf/desc fp32 tables -> bf16 tables (fully coalesced).
__global__ void pack_convert(const float* __restrict__ We, const float* __restrict__ Wq,
                             const float* __restrict__ Wk, const float* __restrict__ Wv,
                             const float* __restrict__ Wc1, const float* __restrict__ Wc2,
                             const float* __restrict__ Wc3,
                             const float* __restrict__ nf, const float* __restrict__ desc,
                             unsigned short* __restrict__ ws) {
    int b = blockIdx.x;
    if (b >= 556) {
        int cb = b - 556;
        const float* src; unsigned short* dst;
        if (cb < 12500) { src = nf;   dst = ws + WOFF_NFB; }
        else            { src = desc; dst = ws + WOFF_DESCB; cb -= 12500; }
        long i = ((long)cb * 256 + threadIdx.x) * 4;
        f32x4 v = *(const f32x4*)(src + i);
        uint2 o;
        o.x = pk_bf16(v[0], v[1]);
        o.y = pk_bf16(v[2], v[3]);
        *(uint2*)(dst + i) = o;
        return;
    }
    const float* src; unsigned short* dst; int KT, NT, ncols;
    if (b < 512) {
        int sel = b >> 7;
        src = sel == 0 ? We : sel == 1 ? Wq : sel == 2 ? Wk : Wv;
        dst = ws + sel * 32768;
        KT = 8; NT = 8; ncols = 128; b &= 127;
    } else if (b < 544) { src = Wc1; dst = ws + 131072; KT = 4; NT = 4; ncols = 64; b -= 512; }
    else if (b < 552)   { src = Wc2; dst = ws + 139264; KT = 2; NT = 2; ncols = 32; b -= 544; }
    else                { src = Wc3; dst = ws + 141312; KT = 1; NT = 2; ncols = 26; b -= 552; }
    int idx = b * 256 + threadIdx.x;
    int total = NT * KT * 64 * 8;
    if (idx >= total) return;
    int j = idx & 7;
    int l = (idx >> 3) & 63;
    int rem = idx >> 9;
    int s = rem % KT;
    int t = rem / KT;
    int k = s * 32 + ((l >> 4) << 3) + j;
    int n = t * 16 + (l & 15);
    dst[idx] = (n < ncols) ? f2bf(src[k * ncols + n]) : (unsigned short)0;
}

template<bool TAB>
__global__ __launch_bounds__(256, 4)
void fused_relcls(const float* __restrict__ nf,
                  const float* __restrict__ desc,
                  const int* __restrict__ sub, const int* __restrict__ obj,
                  const unsigned short* __restrict__ nfb, const unsigned short* __restrict__ descb,
                  const unsigned short* __restrict__ wef, const unsigned short* __restrict__ wqf,
                  const unsigned short* __restrict__ wkf, const unsigned short* __restrict__ wvf,
                  const unsigned short* __restrict__ wc1f, const unsigned short* __restrict__ wc2f,
                  const unsigned short* __restrict__ wc3f,
                  const float* __restrict__ be, const float* __restrict__ bq,
                  const float* __restrict__ bk, const float* __restrict__ bv,
                  const float* __restrict__ bc1, const float* __restrict__ bc2,
                  const float* __restrict__ bc3,
                  float* __restrict__ out)
{
    // 33792 + 1024 = 34816 B LDS -> 4 blocks/CU.
    __shared__ __align__(16) unsigned short Abuf[16896];
    __shared__ float ssm[TM * 4];
    unsigned short* h1Buf = Abuf + 8704;
    unsigned short* h2Buf = Abuf + 13312;

    const int t  = threadIdx.x;
    const int w  = t >> 6;       // wave 0..3 (owns cols [w*32, w*32+32))
    const int l  = t & 63;
    const int cl = l & 15;       // chunk slot / col-in-tile / row-in-tile
    const int cq = l >> 4;       // quad / row-in-group
    const long e0 = (long)blockIdx.x * TM;
    const int wu = __builtin_amdgcn_readfirstlane(w);
    const int rbase = wu * 16;   // wave stages rows [rbase, rbase+16)
    const int g0 = wu * 4;       // wave's first group index

    // per-lane source chunk for staging (XOR swizzle, LDS dest linear):
    const int schunk = (cl ^ cq) << 3;   // ush offset of fetched 16B chunk

    // per-lane base for a-fragment reads:
    //   row = m*16+cl -> group m*4+(cl>>2), in-group row rq=cl&3
    //   chunk c=(ks&3)*4+cq lives at slot (ks&3)*4 + (cq^rq)
    //   addr = m*2112 + (cl>>2)*528 + (cl&3)*128 + (cq^(cl&3))*8 + (ks&3)*32   (ush)
    const int abase = (cl >> 2) * GRP + (cl & 3) * 128 + ((cq ^ (cl & 3)) << 3);

    // ---------------- stage geo planes (async direct-to-LDS, swizzled source) ----------------
    if constexpr (TAB) {
        int si4[4], oi4[4];
        #pragma unroll
        for (int g = 0; g < 4; ++g) {
            int r = rbase + g * 4 + cq;
            si4[g] = sub[e0 + r];
            oi4[g] = obj[e0 + r];
        }
        #pragma unroll
        for (int g = 0; g < 4; ++g) {
            gload_lds16(nfb + (long)si4[g] * HD + schunk, &Abuf[(g0 + g) * GRP]);
            gload_lds16(nfb + (long)oi4[g] * HD + schunk, &Abuf[PL1 + (g0 + g) * GRP]);
        }
    } else {
        #pragma unroll
        for (int g = 0; g < 4; ++g) {
            int r = rbase + g * 4 + cq;
            int si = sub[e0 + r], oi = obj[e0 + r];
            int dst = (g0 + g) * GRP + cq * 128 + cl * 8;
            f32x4 v0 = *(const f32x4*)(nf + (long)si * HD + schunk);
            f32x4 v1 = *(const f32x4*)(nf + (long)si * HD + schunk + 4);
            uint4v o;
            o.x = pk_bf16(v0[0], v0[1]); o.y = pk_bf16(v0[2], v0[3]);
            o.z = pk_bf16(v1[0], v1[1]); o.w = pk_bf16(v1[2], v1[3]);
            *(uint4v*)&Abuf[dst] = o;
            f32x4 u0 = *(const f32x4*)(nf + (long)oi * HD + schunk);
            f32x4 u1 = *(const f32x4*)(nf + (long)oi * HD + schunk + 4);
            uint4v o2;
            o2.x = pk_bf16(u0[0], u0[1]); o2.y = pk_bf16(u0[2], u0[3]);
            o2.z = pk_bf16(u1[0], u1[1]); o2.w = pk_bf16(u1[2], u1[3]);
            *(uint4v*)&Abuf[PL1 + dst] = o2;
        }
    }
    __syncthreads();   // B1 (vmcnt(0) drains the staging loads)

    f32x4 acc0[4][2], acc1[4][2];   // two live accumulator matrices (64 AGPR peak)
    unsigned int opk[16];           // origin parked as packed bf16

    // ---------------- O-phase: origin = geo@We + be -> pack to opk ----------------
    {
        float b0 = be[w * 32 + cl], b1 = be[w * 32 + 16 + cl];
        #pragma unroll
        for (int m = 0; m < 4; ++m) {
            acc0[m][0] = (f32x4){b0, b0, b0, b0};
            acc0[m][1] = (f32x4){b1, b1, b1, b1};
        }
        #pragma unroll
        for (int ks = 0; ks < 8; ++ks) {
            const unsigned short* pl = Abuf + ((ks < 4) ? 0 : PL1);
            short8 a[4];
            #pragma unroll
            for (int m = 0; m < 4; ++m)
                a[m] = *(const short8*)&pl[m * 2112 + abase + (ks & 3) * 32];
            short8 bw[2];
            #pragma unroll
            for (int tt = 0; tt < 2; ++tt)
                bw[tt] = *(const short8*)&wef[(((w * 2 + tt) * 8 + ks) * 64 + l) * 8];
            #pragma unroll
            for (int m = 0; m < 4; ++m)
                #pragma unroll
                for (int tt = 0; tt < 2; ++tt)
                    acc0[m][tt] = __builtin_amdgcn_mfma_f32_16x16x32_bf16(a[m], bw[tt], acc0[m][tt], 0, 0, 0);
        }
        #pragma unroll
        for (int m = 0; m < 4; ++m)
            #pragma unroll
            for (int tt = 0; tt < 2; ++tt) {
                opk[m * 4 + tt * 2 + 0] = pk_bf16(acc0[m][tt][0], acc0[m][tt][1]);
                opk[m * 4 + tt * 2 + 1] = pk_bf16(acc0[m][tt][2], acc0[m][tt][3]);
            }
    }

    // ---------------- Q-phase: query = geo@Wq + bq (reuses acc0) ----------------
    {
        float b0 = bq[w * 32 + cl], b1 = bq[w * 32 + 16 + cl];
        #pragma unroll
        for (int m = 0; m < 4; ++m) {
            acc0[m][0] = (f32x4){b0, b0, b0, b0};
            acc0[m][1] = (f32x4){b1, b1, b1, b1};
        }
        #pragma unroll
        for (int ks = 0; ks < 8; ++ks) {
            const unsigned short* pl = Abuf + ((ks < 4) ? 0 : PL1);
            short8 a[4];
            #pragma unroll
            for (int m = 0; m < 4; ++m)
                a[m] = *(const short8*)&pl[m * 2112 + abase + (ks & 3) * 32];
            short8 bw[2];
            #pragma unroll
            for (int tt = 0; tt < 2; ++tt)
                bw[tt] = *(const short8*)&wqf[(((w * 2 + tt) * 8 + ks) * 64 + l) * 8];
            #pragma unroll
            for (int m = 0; m < 4; ++m)
                #pragma unroll
                for (int tt = 0; tt < 2; ++tt)
                    acc0[m][tt] = __builtin_amdgcn_mfma_f32_16x16x32_bf16(a[m], bw[tt], acc0[m][tt], 0, 0, 0);
        }
    }
    __syncthreads();   // B2: all geo reads done

    // ---------------- stage desc planes (same swizzled scheme) ----------------
    if constexpr (TAB) {
        int si4[4], oi4[4];
        #pragma unroll
        for (int g = 0; g < 4; ++g) {
            int r = rbase + g * 4 + cq;
            si4[g] = sub[e0 + r];
            oi4[g] = obj[e0 + r];
        }
        #pragma unroll
        for (int g = 0; g < 4; ++g) {
            gload_lds16(descb + (long)si4[g] * HD + schunk, &Abuf[(g0 + g) * GRP]);
            gload_lds16(descb + (long)oi4[g] * HD + schunk, &Abuf[PL1 + (g0 + g) * GRP]);
        }
    } else {
        #pragma unroll
        for (int g = 0; g < 4; ++g) {
            int r = rbase + g * 4 + cq;
            int si = sub[e0 + r], oi = obj[e0 + r];
            int dst = (g0 + g) * GRP + cq * 128 + cl * 8;
            f32x4 v0 = *(const f32x4*)(desc + (long)si * HD + schunk);
            f32x4 v1 = *(const f32x4*)(desc + (long)si * HD + schunk + 4);
            uint4v o;
            o.x = pk_bf16(v0[0], v0[1]); o.y = pk_bf16(v0[2], v0[3]);
            o.z = pk_bf16(v1[0], v1[1]); o.w = pk_bf16(v1[2], v1[3]);
            *(uint4v*)&Abuf[dst] = o;
            f32x4 u0 = *(const f32x4*)(desc + (long)oi * HD + schunk);
            f32x4 u1 = *(const f32x4*)(desc + (long)oi * HD + schunk + 4);
            uint4v o2;
            o2.x = pk_bf16(u0[0], u0[1]); o2.y = pk_bf16(u0[2], u0[3]);
            o2.z = pk_bf16(u1[0], u1[1]); o2.w = pk_bf16(u1[2], u1[3]);
            *(uint4v*)&Abuf[PL1 + dst] = o2;
        }
    }
    __syncthreads();   // B3

    // ---------------- K-phase: key = desc@Wk + bk -> acc1; S = Q.*K in acc0 ----------------
    {
        float b0 = bk[w * 32 + cl], b1 = bk[w * 32 + 16 + cl];
        #pragma unroll
        for (int m = 0; m < 4; ++m) {
            acc1[m][0] = (f32x4){b0, b0, b0, b0};
            acc1[m][1] = (f32x4){b1, b1, b1, b1};
        }
        #pragma unroll
        for (int ks = 0; ks < 8; ++ks) {
            const unsigned short* pl = Abuf + ((ks < 4) ? 0 : PL1);
            short8 a[4];
            #pragma unroll
            for (int m = 0; m < 4; ++m)
                a[m] = *(const short8*)&pl[m * 2112 + abase + (ks & 3) * 32];
            short8 bw[2];
            #pragma unroll
            for (int tt = 0; tt < 2; ++tt)
                bw[tt] = *(const short8*)&wkf[(((w * 2 + tt) * 8 + ks) * 64 + l) * 8];
            #pragma unroll
            for (int m = 0; m < 4; ++m)
                #pragma unroll
                for (int tt = 0; tt < 2; ++tt)
                    acc1[m][tt] = __builtin_amdgcn_mfma_f32_16x16x32_bf16(a[m], bw[tt], acc1[m][tt], 0, 0, 0);
        }
        #pragma unroll
        for (int m = 0; m < 4; ++m)
            #pragma unroll
            for (int tt = 0; tt < 2; ++tt)
                acc0[m][tt] *= acc1[m][tt];     // S = q .* k (acc1 now free)
    }

    // ---------------- softmax partials; store exp(S) back into acc0 ----------------
    {
        #pragma unroll
        for (int m = 0; m < 4; ++m) {
            float es[4];
            #pragma unroll
            for (int r = 0; r < 4; ++r) {
                float ea = __expf(acc0[m][0][r]);
                float eb = __expf(acc0[m][1][r]);
                acc0[m][0][r] = ea;
                acc0[m][1][r] = eb;
                float s = ea + eb;
                s += __shfl_xor(s, 1);
                s += __shfl_xor(s, 2);
                s += __shfl_xor(s, 4);
                s += __shfl_xor(s, 8);
                es[r] = s;
            }
            if (cl == 0) {
                #pragma unroll
                for (int r = 0; r < 4; ++r)
                    ssm[(m * 16 + cq * 4 + r) * 4 + w] = es[r];
            }
        }
    }

    // ---------------- V-phase: value = desc@Wv + bv -> acc1 ----------------
    {
        float b0 = bv[w * 32 + cl], b1 = bv[w * 32 + 16 + cl];
        #pragma unroll
        for (int m = 0; m < 4; ++m) {
            acc1[m][0] = (f32x4){b0, b0, b0, b0};
            acc1[m][1] = (f32x4){b1, b1, b1, b1};
        }
        #pragma unroll
        for (int ks = 0; ks < 8; ++ks) {
            const unsigned short* pl = Abuf + ((ks < 4) ? 0 : PL1);
            short8 a[4];
            #pragma unroll
            for (int m = 0; m < 4; ++m)
                a[m] = *(const short8*)&pl[m * 2112 + abase + (ks & 3) * 32];
            short8 bw[2];
            #pragma unroll
            for (int tt = 0; tt < 2; ++tt)
                bw[tt] = *(const short8*)&wvf[(((w * 2 + tt) * 8 + ks) * 64 + l) * 8];
            #pragma unroll
            for (int m = 0; m < 4; ++m)
                #pragma unroll
                for (int tt = 0; tt < 2; ++tt)
                    acc1[m][tt] = __builtin_amdgcn_mfma_f32_16x16x32_bf16(a[m], bw[tt], acc1[m][tt], 0, 0, 0);
        }
    }
    __syncthreads();   // B4: desc reads done, softmax partials visible

    // ---------------- fused = V*alpha + O -> LDS bf16 (A-layout, stride LDF) ----------------
    {
        unsigned short* fusedBuf = Abuf;
        #pragma unroll
        for (int m = 0; m < 4; ++m)
            #pragma unroll
            for (int r = 0; r < 4; ++r) {
                int row = m * 16 + cq * 4 + r;
                f32x4 b = *(const f32x4*)&ssm[row * 4];
                float inv = 1.0f / (b[0] + b[1] + b[2] + b[3]);
                #pragma unroll
                for (int tt = 0; tt < 2; ++tt) {
                    unsigned int word = opk[m * 4 + tt * 2 + (r >> 1)];
                    unsigned short us = (r & 1) ? (unsigned short)(word >> 16) : (unsigned short)(word & 0xffffu);
                    float Oval = bf2f(us);
                    float alpha = acc0[m][tt][r] * inv;
                    float f = acc1[m][tt][r] * alpha + Oval;
                    fusedBuf[row * LDF + w * 32 + tt * 16 + cl] = f2bf(f);
                }
            }
    }
    __syncthreads();   // B5

    // ---------------- classifier L1: [64,128]@[128,64] + relu ----------------
    {
        const unsigned short* fusedBuf = Abuf;
        float b1 = bc1[w * 16 + cl];
        f32x4 acc[4];
        #pragma unroll
        for (int m = 0; m < 4; ++m) acc[m] = (f32x4){b1, b1, b1, b1};
        #pragma unroll
        for (int ks = 0; ks < 4; ++ks) {
            short8 a[4];
            #pragma unroll
            for (int m = 0; m < 4; ++m)
                a[m] = *(const short8*)&fusedBuf[(m * 16 + cl) * LDF + ks * 32 + cq * 8];
            short8 bw = *(const short8*)&wc1f[((w * 4 + ks) * 64 + l) * 8];
            #pragma unroll
            for (int m = 0; m < 4; ++m)
                acc[m] = __builtin_amdgcn_mfma_f32_16x16x32_bf16(a[m], bw, acc[m], 0, 0, 0);
        }
        #pragma unroll
        for (int m = 0; m < 4; ++m)
            #pragma unroll
            for (int r = 0; r < 4; ++r)
                h1Buf[(m * 16 + cq * 4 + r) * LDH1 + w * 16 + cl] = f2bf(fmaxf(acc[m][r], 0.f));
    }
    __syncthreads();   // B6

    // ---------------- classifier L2: [64,64]@[64,32] (no relu) ----------------
    {
        int tn = w & 1, mh = w >> 1;
        float b2 = bc2[tn * 16 + cl];
        f32x4 acc[2];
        acc[0] = (f32x4){b2, b2, b2, b2};
        acc[1] = (f32x4){b2, b2, b2, b2};
        #pragma unroll
        for (int ks = 0; ks < 2; ++ks) {
            short8 a[2];
            #pragma unroll
            for (int mm = 0; mm < 2; ++mm)
                a[mm] = *(const short8*)&h1Buf[((mh * 2 + mm) * 16 + cl) * LDH1 + ks * 32 + cq * 8];
            short8 bw = *(const short8*)&wc2f[((tn * 2 + ks) * 64 + l) * 8];
            #pragma unroll
            for (int mm = 0; mm < 2; ++mm)
                acc[mm] = __builtin_amdgcn_mfma_f32_16x16x32_bf16(a[mm], bw, acc[mm], 0, 0, 0);
        }
        #pragma unroll
        for (int mm = 0; mm < 2; ++mm)
            #pragma unroll
            for (int r = 0; r < 4; ++r)
                h2Buf[((mh * 2 + mm) * 16 + cq * 4 + r) * LDH2 + tn * 16 + cl] = f2bf(acc[mm][r]);
    }
    __syncthreads();   // B7

    // ---------------- classifier L3: [64,32]@[32,26] -> stage f32 in LDS ----------------
    {
        f32x4 acc[2];
        #pragma unroll
        for (int tt = 0; tt < 2; ++tt) {
            int col = tt * 16 + cl;
            float b3 = (col < 26) ? bc3[col] : 0.f;
            acc[tt] = (f32x4){b3, b3, b3, b3};
        }
        short8 a = *(const short8*)&h2Buf[(w * 16 + cl) * LDH2 + cq * 8];
        #pragma unroll
        for (int tt = 0; tt < 2; ++tt)
            acc[tt] = __builtin_amdgcn_mfma_f32_16x16x32_bf16(a, *(const short8*)&wc3f[(tt * 64 + l) * 8], acc[tt], 0, 0, 0);
        float* ostg = (float*)Abuf;
        #pragma unroll
        for (int tt = 0; tt < 2; ++tt) {
            int col = tt * 16 + cl;
            if (col < 26) {
                #pragma unroll
                for (int r = 0; r < 4; ++r)
                    ostg[(w * 16 + cq * 4 + r) * 26 + col] = acc[tt][r];
            }
        }
    }
    __syncthreads();   // B8

    // ---------------- coalesced block output: 6656 contiguous bytes as 416 x 16B ----------------
    {
        const uint4v* src = (const uint4v*)Abuf;
        uint4v* dst = (uint4v*)(out + e0 * 26);
        #pragma unroll
        for (int k2 = 0; k2 < 2; ++k2) {
            int idx = t + k2 * 256;
            if (idx < 416)
                dst[idx] = src[idx];
        }
    }
}

extern "C" void kernel_launch(void* const* d_in, const int* in_sizes, int n_in,
                              void* d_out, int out_size, void* d_ws, size_t ws_size,
                              hipStream_t stream) {
    const float* nf   = (const float*)d_in[0];
    const float* desc = (const float*)d_in[1];
    const int* sub = (const int*)d_in[2];
    const int* obj = (const int*)d_in[3];
    const float* We  = (const float*)d_in[4];
    const float* be  = (const float*)d_in[5];
    const float* Wq  = (const float*)d_in[6];
    const float* bq  = (const float*)d_in[7];
    const float* Wk  = (const float*)d_in[8];
    const float* bk  = (const float*)d_in[9];
    const float* Wv  = (const float*)d_in[10];
    const float* bv  = (const float*)d_in[11];
    const float* Wc1 = (const float*)d_in[12];
    const float* bc1 = (const float*)d_in[13];
    const float* Wc2 = (const float*)d_in[14];
    const float* bc2 = (const float*)d_in[15];
    const float* Wc3 = (const float*)d_in[16];
    const float* bc3 = (const float*)d_in[17];

    unsigned short* ws = (unsigned short*)d_ws;
    unsigned short* wef  = ws;                 // 8*8*64*8  = 32768 elems
    unsigned short* wqf  = ws + 32768;
    unsigned short* wkf  = ws + 65536;
    unsigned short* wvf  = ws + 98304;
    unsigned short* wc1f = ws + 131072;        // 4*4*64*8 = 8192
    unsigned short* wc2f = ws + 139264;        // 2*2*64*8 = 2048
    unsigned short* wc3f = ws + 141312;        // 1*2*64*8 = 1024
    unsigned short* nfb   = ws + WOFF_NFB;     // 12.8M elems (25.6 MB)
    unsigned short* descb = ws + WOFF_DESCB;   // 12.8M elems (25.6 MB)

    const bool tab = (ws_size >= WS_NEED);
    const int prep_grid = tab ? (556 + 25000) : 556;

    pack_convert<<<prep_grid, 256, 0, stream>>>(We, Wq, Wk, Wv, Wc1, Wc2, Wc3, nf, desc, ws);

    if (tab) {
        fused_relcls<true><<<NEDGE / TM, 256, 0, stream>>>(
            nf, desc, sub, obj, nfb, descb,
            wef, wqf, wkf, wvf, wc1f, wc2f, wc3f,
            be, bq, bk, bv, bc1, bc2, bc3,
            (float*)d_out);
    } else {
        fused_relcls<false><<<NEDGE / TM, 256, 0, stream>>>(
            nf, desc, sub, obj, nfb, descb,
            wef, wqf, wkf, wvf, wc1f, wc2f, wc3f,
            be, bq, bk, bv, bc1, bc2, bc3,
            (float*)d_out);
    }
}